// Round 4
// baseline (96.068 us; speedup 1.0000x reference)
//
#include <hip/hip_runtime.h>
#include <math.h>

#define IW 256
#define IH 256
#define NG 1000
#define NSEG 8
#define SEG (NG / NSEG)   // 125
#define ALPHA_MAX 0.999f

// Kernel 1: per-gaussian coefficient precompute -> global params array.
// params[2n]   = (cx, cy, A', B')
// params[2n+1] = (C', log2(opac), color, 0)
// where exponent e = A'*dx^2 + B'*dx*dy + C'*dy^2 + log2(opac), alpha = 2^e.
// (-0.5, inverse covariance, and 1/ln2 all folded into A',B',C'.)
__global__ __launch_bounds__(256) void splat2d_precompute_kernel(
    const float* __restrict__ means,
    const float* __restrict__ quats,
    const float* __restrict__ scales,
    const float* __restrict__ rgbs,
    const float* __restrict__ opacities,
    float4* __restrict__ params)
{
    const int n = blockIdx.x * 256 + threadIdx.x;
    if (n >= NG) return;

    const float INV_LN2 = 1.4426950408889634f;
    float cx = means[2 * n + 0];
    float cy = means[2 * n + 1];
    float q  = quats[n];
    float sx = scales[2 * n + 0];
    float sy = scales[2 * n + 1];
    float cq = cosf(q), sq = sinf(q);
    float sx2 = sx * sx, sy2 = sy * sy;
    float a11 = cq * cq * sx2 + sq * sq * sy2;
    float a12 = cq * sq * (sx2 - sy2);
    float a22 = sq * sq * sx2 + cq * cq * sy2;
    float det = a11 * a22 - a12 * a12;
    float inv = INV_LN2 / det;
    float A  = -0.5f * a22 * inv;
    float B  =          a12 * inv;
    float Cc = -0.5f * a11 * inv;
    float op  = 1.0f / (1.0f + expf(-opacities[n]));
    float lop = log2f(op);
    float col = 1.0f / (1.0f + expf(-rgbs[n]));
    params[2 * n + 0] = make_float4(cx, cy, A, B);
    params[2 * n + 1] = make_float4(Cc, lop, col, 0.0f);
}

// Kernel 2: block (y, s) composites gaussians [s*SEG, (s+1)*SEG) for row y.
// Params are read with wave-uniform indices -> scalar (s_load) path, no LDS.
__global__ __launch_bounds__(256) void splat2d_segment_kernel(
    const float4* __restrict__ params,
    float2* __restrict__ segout)         // NSEG x H x W
{
    const int tid = threadIdx.x;
    const int y   = blockIdx.x;
    const int s   = blockIdx.y;
    const int n0g = s * SEG;

    const float px = (float)tid + 0.5f;
    const float py = (float)y + 0.5f;

    float T = 1.0f;
    float accum = 0.0f;

    #pragma unroll 5
    for (int k = 0; k < SEG; ++k) {
        float4 q0 = params[2 * (n0g + k) + 0];
        float4 q1 = params[2 * (n0g + k) + 1];
        float dx = px - q0.x;
        float dy = py - q0.y;
        float t  = fmaf(q0.w, dy, q0.z * dx);              // A'*dx + B'*dy
        float e  = fmaf(t, dx, fmaf(q1.x * dy, dy, q1.y)); // + C'*dy^2 + lop
        float alpha = fminf(__builtin_amdgcn_exp2f(e), ALPHA_MAX);
        accum = fmaf(alpha * T, q1.z, accum);
        T = fmaf(-alpha, T, T);
    }

    segout[(s * IH + y) * IW + tid] = make_float2(accum, T);
}

// Kernel 3: per pixel, fold the NSEG (c, T) partials in order.
__global__ __launch_bounds__(256) void splat2d_combine_kernel(
    const float2* __restrict__ segout,
    float* __restrict__ out)
{
    const int pix = blockIdx.x * 256 + threadIdx.x;

    float c = 0.0f;
    float T = 1.0f;
    #pragma unroll
    for (int s = 0; s < NSEG; ++s) {
        float2 v = segout[s * (IH * IW) + pix];
        c = fmaf(T, v.x, c);
        T *= v.y;
    }
    out[pix] = c;
}

extern "C" void kernel_launch(void* const* d_in, const int* in_sizes, int n_in,
                              void* d_out, int out_size, void* d_ws, size_t ws_size,
                              hipStream_t stream) {
    const float* means     = (const float*)d_in[0];
    const float* quats     = (const float*)d_in[1];
    const float* scales    = (const float*)d_in[2];
    const float* rgbs      = (const float*)d_in[3];
    const float* opacities = (const float*)d_in[4];
    float* out = (float*)d_out;

    float4* params = (float4*)d_ws;                        // 2*NG float4 = 32 KB
    float2* segout = (float2*)((char*)d_ws + 32768);       // NSEG*IH*IW float2 = 4 MiB

    splat2d_precompute_kernel<<<(NG + 255) / 256, 256, 0, stream>>>(
        means, quats, scales, rgbs, opacities, params);
    splat2d_segment_kernel<<<dim3(IH, NSEG), 256, 0, stream>>>(params, segout);
    splat2d_combine_kernel<<<(IH * IW) / 256, 256, 0, stream>>>(segout, out);
}

// Round 5
// 73.365 us; speedup vs baseline: 1.3094x; 1.3094x over previous
//
#include <hip/hip_runtime.h>
#include <math.h>

#define IW 256
#define IH 256
#define NG 1000
#define NSEG 4
#define SEG (NG / NSEG)    // 250
#define TILE_W 32
#define TILE_H 8
#define TILES_X (IW / TILE_W)   // 8
#define TILES_Y (IH / TILE_H)   // 32
#define ALPHA_MAX 0.999f
#define LOG2_EPS -19.93157f     // log2(1e-6) cull threshold
#define LN2 0.6931471805599453f

// K1: per-gaussian precompute.
// ga[n] = (cx, cy, rx, ry)        -- cull box half-extents at alpha=eps
// gb[n] = (A, B, C, lop)          -- alpha = 2^(A dx^2 + B dx dy + C dy^2 + lop)
// gc[n] = col
__global__ __launch_bounds__(256) void splat2d_precompute_kernel(
    const float* __restrict__ means,
    const float* __restrict__ quats,
    const float* __restrict__ scales,
    const float* __restrict__ rgbs,
    const float* __restrict__ opacities,
    float4* __restrict__ ga,
    float4* __restrict__ gb,
    float* __restrict__ gc)
{
    const int n = blockIdx.x * 256 + threadIdx.x;
    if (n >= NG) return;

    const float INV_LN2 = 1.4426950408889634f;
    float cx = means[2 * n + 0];
    float cy = means[2 * n + 1];
    float q  = quats[n];
    float sx = scales[2 * n + 0];
    float sy = scales[2 * n + 1];
    float cq = cosf(q), sq = sinf(q);
    float sx2 = sx * sx, sy2 = sy * sy;
    float a11 = cq * cq * sx2 + sq * sq * sy2;
    float a12 = cq * sq * (sx2 - sy2);
    float a22 = sq * sq * sx2 + cq * cq * sy2;
    float det = a11 * a22 - a12 * a12;
    float inv = INV_LN2 / det;
    float A  = -0.5f * a22 * inv;
    float B  =          a12 * inv;
    float Cc = -0.5f * a11 * inv;
    float op  = 1.0f / (1.0f + expf(-opacities[n]));
    float lop = log2f(op);
    float col = 1.0f / (1.0f + expf(-rgbs[n]));

    // ln(op/eps) = (lop - log2eps)*ln2 ; support radius where alpha >= eps
    float t = fmaxf((lop - LOG2_EPS) * LN2, 0.0f);
    float rx = sqrtf(2.0f * a11 * t);
    float ry = sqrtf(2.0f * a22 * t);

    ga[n] = make_float4(cx, cy, rx, ry);
    gb[n] = make_float4(A, B, Cc, lop);
    gc[n] = col;
}

// K2: block (tile_x, tile_y, seg). Compact surviving gaussians of the segment
// into LDS (index order preserved), then scan-composite over the tile's pixels.
__global__ __launch_bounds__(256) void splat2d_segment_kernel(
    const float4* __restrict__ ga,
    const float4* __restrict__ gb,
    const float* __restrict__ gc,
    float2* __restrict__ segout)         // NSEG x H x W
{
    __shared__ float4 s0[SEG];   // cx, cy, A, B
    __shared__ float4 s1[SEG];   // C, lop, col, 0
    __shared__ int wave_cnt[4];
    __shared__ int s_count;

    const int tid = threadIdx.x;
    const int tx0 = blockIdx.x * TILE_W;
    const int ty0 = blockIdx.y * TILE_H;
    const int s   = blockIdx.z;
    const int n0g = s * SEG;

    // --- cull + compact (order-preserving) ---
    const float midx = (float)tx0 + 0.5f * (TILE_W - 1) + 0.5f;  // tile center x
    const float midy = (float)ty0 + 0.5f * (TILE_H - 1) + 0.5f;
    const float hx = 0.5f * (TILE_W - 1);                        // 15.5
    const float hy = 0.5f * (TILE_H - 1);                        // 3.5

    bool keep = false;
    float4 a4;
    if (tid < SEG) {
        a4 = ga[n0g + tid];
        keep = (fabsf(a4.x - midx) <= hx + a4.z) &&
               (fabsf(a4.y - midy) <= hy + a4.w);
    }

    unsigned long long m = __ballot(keep);
    const int lane = tid & 63;
    const int w    = tid >> 6;
    int rank = __popcll(m & ((1ull << lane) - 1ull));
    if (lane == 0) wave_cnt[w] = __popcll(m);
    __syncthreads();
    int off = 0;
    #pragma unroll
    for (int i = 0; i < 4; ++i) if (i < w) off += wave_cnt[i];
    if (keep) {
        float4 b4 = gb[n0g + tid];
        float  c  = gc[n0g + tid];
        s0[off + rank] = make_float4(a4.x, a4.y, b4.x, b4.y);
        s1[off + rank] = make_float4(b4.z, b4.w, c, 0.0f);
    }
    if (tid == 0) s_count = wave_cnt[0] + wave_cnt[1] + wave_cnt[2] + wave_cnt[3];
    __syncthreads();

    // --- scan-composite ---
    const float px = (float)(tx0 + (tid & (TILE_W - 1))) + 0.5f;
    const float py = (float)(ty0 + (tid >> 5)) + 0.5f;
    const int cnt = s_count;

    float T = 1.0f;
    float accum = 0.0f;

    for (int k = 0; k < cnt; ++k) {
        float4 q0 = s0[k];
        float4 q1 = s1[k];
        float dx = px - q0.x;
        float dy = py - q0.y;
        float t  = fmaf(q0.w, dy, q0.z * dx);               // A*dx + B*dy
        float e  = fmaf(t, dx, fmaf(q1.x * dy, dy, q1.y));  // + C*dy^2 + lop
        float alpha = fminf(__builtin_amdgcn_exp2f(e), ALPHA_MAX);
        accum = fmaf(alpha * T, q1.z, accum);
        T = fmaf(-alpha, T, T);
        if (((k & 7) == 7) && __all(T < 1e-5f)) break;
    }

    const int pix = (ty0 + (tid >> 5)) * IW + tx0 + (tid & (TILE_W - 1));
    segout[s * (IH * IW) + pix] = make_float2(accum, T);
}

// K3: fold the NSEG (c, T) partials in order per pixel.
__global__ __launch_bounds__(256) void splat2d_combine_kernel(
    const float2* __restrict__ segout,
    float* __restrict__ out)
{
    const int pix = blockIdx.x * 256 + threadIdx.x;

    float c = 0.0f;
    float T = 1.0f;
    #pragma unroll
    for (int s = 0; s < NSEG; ++s) {
        float2 v = segout[s * (IH * IW) + pix];
        c = fmaf(T, v.x, c);
        T *= v.y;
    }
    out[pix] = c;
}

extern "C" void kernel_launch(void* const* d_in, const int* in_sizes, int n_in,
                              void* d_out, int out_size, void* d_ws, size_t ws_size,
                              hipStream_t stream) {
    const float* means     = (const float*)d_in[0];
    const float* quats     = (const float*)d_in[1];
    const float* scales    = (const float*)d_in[2];
    const float* rgbs      = (const float*)d_in[3];
    const float* opacities = (const float*)d_in[4];
    float* out = (float*)d_out;

    char* ws = (char*)d_ws;
    float4* ga = (float4*)(ws);                       // 16 KB
    float4* gb = (float4*)(ws + 16384);               // 16 KB
    float*  gc = (float*)(ws + 32768);                // 4 KB
    float2* segout = (float2*)(ws + 65536);           // NSEG*IH*IW*8 = 2 MiB

    splat2d_precompute_kernel<<<(NG + 255) / 256, 256, 0, stream>>>(
        means, quats, scales, rgbs, opacities, ga, gb, gc);
    splat2d_segment_kernel<<<dim3(TILES_X, TILES_Y, NSEG), 256, 0, stream>>>(
        ga, gb, gc, segout);
    splat2d_combine_kernel<<<(IH * IW) / 256, 256, 0, stream>>>(segout, out);
}

// Round 6
// 70.779 us; speedup vs baseline: 1.3573x; 1.0365x over previous
//
#include <hip/hip_runtime.h>
#include <math.h>

#define IW 256
#define IH 256
#define NG 1000
#define NSEG 4
#define SEG (NG / NSEG)    // 250
#define TILE_W 32
#define TILE_H 8
#define TILES_X (IW / TILE_W)   // 8
#define TILES_Y (IH / TILE_H)   // 32
#define ALPHA_MAX 0.999f
#define LOG2_EPS -19.93157f     // log2(1e-6) cull threshold
#define LN2 0.6931471805599453f
#define INV_LN2 1.4426950408889634f

// K1 (fused): block (tile_x, tile_y, seg).
//  Phase A: tid<SEG computes gaussian n0g+tid params in-register:
//           cx, cy, A, B, C, lop, col, rx, ry
//           where alpha = 2^(A dx^2 + B dx dy + C dy^2 + lop),
//           (rx, ry) = support box half-extents at alpha = 1e-6.
//  Phase B: cull vs tile AABB, ballot+prefix compact keepers into LDS
//           (index order preserved).
//  Phase C: per-pixel ordered scan-composite, write (c, T) partial.
__global__ __launch_bounds__(256) void splat2d_segment_kernel(
    const float* __restrict__ means,
    const float* __restrict__ quats,
    const float* __restrict__ scales,
    const float* __restrict__ rgbs,
    const float* __restrict__ opacities,
    float2* __restrict__ segout)         // NSEG x H x W
{
    __shared__ float4 s0[SEG];   // cx, cy, A, B
    __shared__ float4 s1[SEG];   // C, lop, col, 0
    __shared__ int wave_cnt[4];
    __shared__ int s_count;

    const int tid = threadIdx.x;
    const int tx0 = blockIdx.x * TILE_W;
    const int ty0 = blockIdx.y * TILE_H;
    const int s   = blockIdx.z;
    const int n0g = s * SEG;

    const float midx = (float)tx0 + 0.5f * (TILE_W - 1) + 0.5f;
    const float midy = (float)ty0 + 0.5f * (TILE_H - 1) + 0.5f;
    const float hx = 0.5f * (TILE_W - 1);
    const float hy = 0.5f * (TILE_H - 1);

    bool keep = false;
    float cx, cy, A, B, Cc, lop, col;
    if (tid < SEG) {
        const int n = n0g + tid;
        float2 mu = ((const float2*)means)[n];
        float2 sc = ((const float2*)scales)[n];
        float q   = quats[n];
        float opa = opacities[n];
        float rgb = rgbs[n];

        float sq, cq;
        __sincosf(q, &sq, &cq);
        float sx2 = sc.x * sc.x, sy2 = sc.y * sc.y;
        float a11 = cq * cq * sx2 + sq * sq * sy2;
        float a12 = cq * sq * (sx2 - sy2);
        float a22 = sq * sq * sx2 + cq * cq * sy2;
        float det = a11 * a22 - a12 * a12;
        float inv = INV_LN2 / det;
        A   = -0.5f * a22 * inv;
        B   =          a12 * inv;
        Cc  = -0.5f * a11 * inv;
        float op = 1.0f / (1.0f + __expf(-opa));
        lop = __log2f(op);
        col = 1.0f / (1.0f + __expf(-rgb));
        cx = mu.x; cy = mu.y;

        // support radii at alpha = eps
        float t  = fmaxf((lop - LOG2_EPS) * LN2, 0.0f);
        float rx = sqrtf(2.0f * a11 * t);
        float ry = sqrtf(2.0f * a22 * t);

        keep = (fabsf(cx - midx) <= hx + rx) &&
               (fabsf(cy - midy) <= hy + ry);
    }

    unsigned long long m = __ballot(keep);
    const int lane = tid & 63;
    const int w    = tid >> 6;
    int rank = __popcll(m & ((1ull << lane) - 1ull));
    if (lane == 0) wave_cnt[w] = __popcll(m);
    __syncthreads();
    int off = 0;
    #pragma unroll
    for (int i = 0; i < 4; ++i) if (i < w) off += wave_cnt[i];
    if (keep) {
        s0[off + rank] = make_float4(cx, cy, A, B);
        s1[off + rank] = make_float4(Cc, lop, col, 0.0f);
    }
    if (tid == 0) s_count = wave_cnt[0] + wave_cnt[1] + wave_cnt[2] + wave_cnt[3];
    __syncthreads();

    // --- scan-composite ---
    const float px = (float)(tx0 + (tid & (TILE_W - 1))) + 0.5f;
    const float py = (float)(ty0 + (tid >> 5)) + 0.5f;
    const int cnt = s_count;

    float T = 1.0f;
    float accum = 0.0f;

    for (int k = 0; k < cnt; ++k) {
        float4 q0 = s0[k];
        float4 q1 = s1[k];
        float dx = px - q0.x;
        float dy = py - q0.y;
        float t  = fmaf(q0.w, dy, q0.z * dx);               // A*dx + B*dy
        float e  = fmaf(t, dx, fmaf(q1.x * dy, dy, q1.y));  // + C*dy^2 + lop
        float alpha = fminf(__builtin_amdgcn_exp2f(e), ALPHA_MAX);
        accum = fmaf(alpha * T, q1.z, accum);
        T = fmaf(-alpha, T, T);
        if (((k & 7) == 7) && __all(T < 1e-5f)) break;
    }

    const int pix = (ty0 + (tid >> 5)) * IW + tx0 + (tid & (TILE_W - 1));
    segout[s * (IH * IW) + pix] = make_float2(accum, T);
}

// K2: fold the NSEG (c, T) partials in order per pixel.
__global__ __launch_bounds__(256) void splat2d_combine_kernel(
    const float2* __restrict__ segout,
    float* __restrict__ out)
{
    const int pix = blockIdx.x * 256 + threadIdx.x;

    float c = 0.0f;
    float T = 1.0f;
    #pragma unroll
    for (int s = 0; s < NSEG; ++s) {
        float2 v = segout[s * (IH * IW) + pix];
        c = fmaf(T, v.x, c);
        T *= v.y;
    }
    out[pix] = c;
}

extern "C" void kernel_launch(void* const* d_in, const int* in_sizes, int n_in,
                              void* d_out, int out_size, void* d_ws, size_t ws_size,
                              hipStream_t stream) {
    const float* means     = (const float*)d_in[0];
    const float* quats     = (const float*)d_in[1];
    const float* scales    = (const float*)d_in[2];
    const float* rgbs      = (const float*)d_in[3];
    const float* opacities = (const float*)d_in[4];
    float* out = (float*)d_out;

    float2* segout = (float2*)d_ws;   // NSEG*IH*IW float2 = 2 MiB

    splat2d_segment_kernel<<<dim3(TILES_X, TILES_Y, NSEG), 256, 0, stream>>>(
        means, quats, scales, rgbs, opacities, segout);
    splat2d_combine_kernel<<<(IH * IW) / 256, 256, 0, stream>>>(segout, out);
}